// Round 1
// baseline (348.955 us; speedup 1.0000x reference)
//
#include <hip/hip_runtime.h>

#define NROW 50000
#define DIN 128
#define DM 256      // D_MODEL
#define HH 4
#define DTOT 1024   // H * D_MODEL
#define NC 40
#define BHN 200000  // BH * N

// -------- Kernel 1: scatter perm values by (head, col) --------
// vcol[h*NROW + col] = v  where nnz k has (b=h, row, col), col = sigma_h(row)
__global__ __launch_bounds__(256) void k_scatter(const int* __restrict__ pi,
                                                 const float* __restrict__ pv,
                                                 float* __restrict__ vcol) {
    int k = blockIdx.x * 256 + threadIdx.x;
    if (k < BHN) {
        int b   = pi[k];
        int col = pi[2 * BHN + k];
        vcol[b * NROW + col] = pv[k];
    }
}

// -------- Kernel 2: g = [features | appd] @ W_in  (50000x256 @ 256x256, f32) --------
// 64x64 C-tile per block, 256 threads, 4x4 micro-tile, BK=64
__global__ __launch_bounds__(256) void k_gemm1(const float* __restrict__ feats,
                                               const float* __restrict__ appd,
                                               const float* __restrict__ Win,
                                               float* __restrict__ g) {
    __shared__ float As[64][68];   // [row][k], padded
    __shared__ float Bs[64][64];   // [k][col]
    const int tid = threadIdx.x;
    const int j0 = blockIdx.x * 64;
    const int c0 = blockIdx.y * 64;
    const int rg = tid & 15;       // row group (rows rg, rg+16, rg+32, rg+48)
    const int cg = tid >> 4;       // col group (cols cg*4 .. cg*4+3)
    float acc[4][4] = {};

    for (int kc = 0; kc < 4; ++kc) {
        // stage A: 64 rows x 64 k
        {
            const int row0 = tid >> 4;   // 0..15 (+16 per q)
            const int k4 = tid & 15;
            const float* src = (kc < 2) ? feats : appd;
            const int gk = kc * 64 + k4 * 4 - ((kc < 2) ? 0 : 128);
            #pragma unroll
            for (int q = 0; q < 4; ++q) {
                int r = row0 + q * 16;
                int jr = j0 + r;
                float4 av = make_float4(0.f, 0.f, 0.f, 0.f);
                if (jr < NROW) av = *(const float4*)&src[jr * DIN + gk];
                *(float4*)&As[r][k4 * 4] = av;
            }
        }
        // stage B: 64 k x 64 cols
        {
            const int kk0 = tid >> 4;
            const int c4 = tid & 15;
            #pragma unroll
            for (int q = 0; q < 4; ++q) {
                int k = kk0 + q * 16;
                float4 bv = *(const float4*)&Win[(kc * 64 + k) * DM + c0 + c4 * 4];
                *(float4*)&Bs[k][c4 * 4] = bv;
            }
        }
        __syncthreads();
        #pragma unroll 4
        for (int kk = 0; kk < 64; ++kk) {
            float a[4];
            a[0] = As[rg][kk];
            a[1] = As[rg + 16][kk];
            a[2] = As[rg + 32][kk];
            a[3] = As[rg + 48][kk];
            float4 b = *(float4*)&Bs[kk][cg * 4];
            #pragma unroll
            for (int i = 0; i < 4; ++i) {
                acc[i][0] += a[i] * b.x;
                acc[i][1] += a[i] * b.y;
                acc[i][2] += a[i] * b.z;
                acc[i][3] += a[i] * b.w;
            }
        }
        __syncthreads();
    }
    #pragma unroll
    for (int i = 0; i < 4; ++i) {
        int jr = j0 + rg + 16 * i;
        if (jr < NROW) {
            float4 o = make_float4(acc[i][0], acc[i][1], acc[i][2], acc[i][3]);
            *(float4*)&g[jr * DM + c0 + cg * 4] = o;
        }
    }
}

// -------- Kernel 3: LayerNorm stats per row (mean, rstd over 1024 = 4 heads x 256) --------
// one wave per row; y2[h*256+dd] = v_h * relu(v_h * g[j,dd] + b_in[dd])
__global__ __launch_bounds__(256) void k_stats(const float* __restrict__ g,
                                               const float* __restrict__ vcol,
                                               const float* __restrict__ b_in,
                                               float* __restrict__ mu,
                                               float* __restrict__ rstd) {
    const int w = threadIdx.x >> 6;
    const int l = threadIdx.x & 63;
    const int j = blockIdx.x * 4 + w;
    float4 gv = *(const float4*)&g[j * DM + l * 4];
    float4 bv = *(const float4*)&b_in[l * 4];
    float sum = 0.f, ss = 0.f;
    #pragma unroll
    for (int h = 0; h < HH; ++h) {
        float v = vcol[h * NROW + j];
        float y;
        y = v * fmaxf(v * gv.x + bv.x, 0.f); sum += y; ss += y * y;
        y = v * fmaxf(v * gv.y + bv.y, 0.f); sum += y; ss += y * y;
        y = v * fmaxf(v * gv.z + bv.z, 0.f); sum += y; ss += y * y;
        y = v * fmaxf(v * gv.w + bv.w, 0.f); sum += y; ss += y * y;
    }
    #pragma unroll
    for (int off = 32; off > 0; off >>= 1) {
        sum += __shfl_down(sum, off);
        ss  += __shfl_down(ss, off);
    }
    if (l == 0) {
        float m = sum * (1.f / DTOT);
        float var = ss * (1.f / DTOT) - m * m;
        mu[j] = m;
        rstd[j] = rsqrtf(var + 1e-5f);
    }
}

// -------- Kernel 4: fused normalize + head GEMM --------
// out[j,c] = sum_d ((y2[j,d]-mu)*rstd*gamma[d]+beta[d]) * Wh[d,c] + bh[c]
// block: 64 rows, 128 threads, BK=64 over d (each chunk is within one head)
__global__ __launch_bounds__(128) void k_head(const float* __restrict__ g,
                                              const float* __restrict__ vcol,
                                              const float* __restrict__ b_in,
                                              const float* __restrict__ gamma,
                                              const float* __restrict__ beta,
                                              const float* __restrict__ Wh,
                                              const float* __restrict__ bh,
                                              const float* __restrict__ mu,
                                              const float* __restrict__ rstd,
                                              float* __restrict__ out) {
    __shared__ float ys[64][65];       // [kk][row], padded -> conflict-free both ways
    __shared__ float Whs[64 * NC];     // [kk][c] flat
    __shared__ float mus[64], rss[64], vs[HH][64];
    const int tid = threadIdx.x;
    const int j0 = blockIdx.x * 64;

    if (tid < 64) {
        int j = min(j0 + tid, NROW - 1);
        mus[tid] = mu[j];
        rss[tid] = rstd[j];
        #pragma unroll
        for (int h = 0; h < HH; ++h) vs[h][tid] = vcol[h * NROW + j];
    }
    __syncthreads();

    const int rg = tid & 15;   // rows rg, rg+16, rg+32, rg+48
    const int cg = tid >> 4;   // 0..7 -> cols cg*5 .. cg*5+4
    float acc[4][5] = {};

    for (int c = 0; c < 16; ++c) {
        const int d0 = c * 64;
        const int h = d0 >> 8;
        const int dd0 = d0 & 255;
        // stage normalized activations: ys[dd][r]
        #pragma unroll 8
        for (int q = 0; q < 32; ++q) {
            int idx = tid + 128 * q;
            int r = idx >> 6;
            int dd = idx & 63;
            int jr = min(j0 + r, NROW - 1);
            float gvv = g[jr * DM + dd0 + dd];
            float v = vs[h][r];
            float y = v * fmaxf(v * gvv + b_in[dd0 + dd], 0.f);
            float yn = (y - mus[r]) * rss[r];
            yn = yn * gamma[d0 + dd] + beta[d0 + dd];
            ys[dd][r] = yn;
        }
        // stage Wh chunk: flat copy of 64*40 floats
        #pragma unroll
        for (int q = 0; q < 20; ++q) {
            int f = tid + 128 * q;
            Whs[f] = Wh[d0 * NC + f];
        }
        __syncthreads();
        #pragma unroll 4
        for (int kk = 0; kk < 64; ++kk) {
            float y[4];
            y[0] = ys[kk][rg];
            y[1] = ys[kk][rg + 16];
            y[2] = ys[kk][rg + 32];
            y[3] = ys[kk][rg + 48];
            float w[5];
            #pragma unroll
            for (int jj = 0; jj < 5; ++jj) w[jj] = Whs[kk * NC + cg * 5 + jj];
            #pragma unroll
            for (int i = 0; i < 4; ++i)
                #pragma unroll
                for (int jj = 0; jj < 5; ++jj) acc[i][jj] += y[i] * w[jj];
        }
        __syncthreads();
    }

    #pragma unroll
    for (int i = 0; i < 4; ++i) {
        int jr = j0 + rg + 16 * i;
        if (jr < NROW) {
            #pragma unroll
            for (int jj = 0; jj < 5; ++jj)
                out[jr * NC + cg * 5 + jj] = acc[i][jj] + bh[cg * 5 + jj];
        }
    }
}

extern "C" void kernel_launch(void* const* d_in, const int* in_sizes, int n_in,
                              void* d_out, int out_size, void* d_ws, size_t ws_size,
                              hipStream_t stream) {
    const int*   pi    = (const int*)d_in[0];
    const float* pv    = (const float*)d_in[1];
    const float* feats = (const float*)d_in[2];
    const float* appd  = (const float*)d_in[3];
    const float* Win   = (const float*)d_in[4];
    const float* b_in  = (const float*)d_in[5];
    const float* gamma = (const float*)d_in[6];
    const float* beta  = (const float*)d_in[7];
    const float* Wh    = (const float*)d_in[8];
    const float* bh    = (const float*)d_in[9];
    float* out = (float*)d_out;

    float* ws   = (float*)d_ws;
    float* g    = ws;                          // NROW*DM
    float* vcol = g + (size_t)NROW * DM;       // HH*NROW
    float* muA  = vcol + (size_t)HH * NROW;    // NROW
    float* rsA  = muA + NROW;                  // NROW

    k_scatter<<<(BHN + 255) / 256, 256, 0, stream>>>(pi, pv, vcol);
    k_gemm1<<<dim3((NROW + 63) / 64, 4), 256, 0, stream>>>(feats, appd, Win, g);
    k_stats<<<NROW / 4, 256, 0, stream>>>(g, vcol, b_in, muA, rsA);
    k_head<<<(NROW + 63) / 64, 128, 0, stream>>>(g, vcol, b_in, gamma, beta, Wh, bh, muA, rsA, out);
}

// Round 2
// 168.667 us; speedup vs baseline: 2.0689x; 2.0689x over previous
//
#include <hip/hip_runtime.h>

#define NROW 50000
#define DIN 128
#define DM 256
#define HH 4
#define NC 40
#define BHN 200000
#define NBLK 782   // ceil(50000/64)

typedef float f32x4 __attribute__((ext_vector_type(4)));
typedef short bf16x8 __attribute__((ext_vector_type(8)));

__device__ __forceinline__ unsigned short f2bf(float x) {
    unsigned int u = __float_as_uint(x);
    u += 0x7fffu + ((u >> 16) & 1u);
    return (unsigned short)(u >> 16);
}

// -------- scatter perm values by (head, col): vcol[h][col] = v --------
__global__ __launch_bounds__(256) void k_scatter(const int* __restrict__ pi,
                                                 const float* __restrict__ pv,
                                                 float* __restrict__ vcol) {
    int k = blockIdx.x * 256 + threadIdx.x;
    if (k < BHN) {
        int b   = pi[k];
        int col = pi[2 * BHN + k];
        vcol[b * NROW + col] = pv[k];
    }
}

// -------- prep: Wt[n][k] = bf16(W_in[k][n])  (256x256) --------
__global__ __launch_bounds__(256) void k_prep_wt(const float* __restrict__ Win,
                                                 unsigned short* __restrict__ Wt) {
    int n = blockIdx.x, k = threadIdx.x;
    Wt[n * DM + k] = f2bf(Win[k * DM + n]);
}

// -------- prep: Wgt[c][d] = bf16(gamma[d]*Wh[d][c]); bias2[c] = bh[c]+sum_d beta[d]*Wh[d][c] --------
__global__ __launch_bounds__(256) void k_prep_wh(const float* __restrict__ Wh,
                                                 const float* __restrict__ gamma,
                                                 const float* __restrict__ beta,
                                                 const float* __restrict__ bh,
                                                 unsigned short* __restrict__ Wgt,
                                                 float* __restrict__ bias2) {
    __shared__ float red[256];
    int c = blockIdx.x, tid = threadIdx.x;
    float part = 0.f;
    #pragma unroll
    for (int q = 0; q < 4; ++q) {
        int d = tid + 256 * q;
        float w = Wh[d * NC + c];
        Wgt[c * 1024 + d] = f2bf(gamma[d] * w);
        part = fmaf(beta[d], w, part);
    }
    red[tid] = part;
    __syncthreads();
    for (int s = 128; s > 0; s >>= 1) {
        if (tid < s) red[tid] += red[tid + s];
        __syncthreads();
    }
    if (tid == 0) bias2[c] = bh[c] + red[0];
}

// -------- fused: G = A@W_in (MFMA) -> stats in-reg -> per-head LN+head GEMM (MFMA) --------
__global__ __launch_bounds__(256, 2) void k_fused(
    const float* __restrict__ feats, const float* __restrict__ appd,
    const unsigned short* __restrict__ Wt,   // [256 n][256 k] bf16
    const unsigned short* __restrict__ Wgt,  // [40 c][1024 d] bf16 (gamma folded)
    const float* __restrict__ vcol,          // [4][NROW]
    const float* __restrict__ b_in,          // [256]
    const float* __restrict__ bias2,         // [40]
    float* __restrict__ out)                 // [NROW][40]
{
    __shared__ __align__(16) unsigned short Abuf[64 * 264];  // A bf16 / z bf16, stride 264
    __shared__ __align__(16) unsigned short Wbuf[48 * 264];  // P1: [256 n][40 k-pad]; P3: [48 c][264]
    __shared__ float vsL[HH][64];
    __shared__ float binL[DM];
    __shared__ float b2L[48];

    const int tid = threadIdx.x;
    const int wv = tid >> 6;
    const int ln = tid & 63;
    const int quad = ln >> 4;
    const int lr = ln & 15;
    const int j0 = blockIdx.x * 64;

    // ---- stage A (64 rows x 256 k -> bf16), params ----
    #pragma unroll
    for (int q = 0; q < 16; ++q) {
        int cid = tid + 256 * q;
        int r = cid >> 6;
        int k4 = (cid & 63) << 2;
        int jr = j0 + r;
        float4 v = make_float4(0.f, 0.f, 0.f, 0.f);
        if (jr < NROW)
            v = (k4 < DIN) ? *(const float4*)&feats[(size_t)jr * DIN + k4]
                           : *(const float4*)&appd[(size_t)jr * DIN + k4 - DIN];
        ushort4 b;
        b.x = f2bf(v.x); b.y = f2bf(v.y); b.z = f2bf(v.z); b.w = f2bf(v.w);
        *(ushort4*)&Abuf[r * 264 + k4] = b;
    }
    if (tid < 64) {
        int j = min(j0 + tid, NROW - 1);
        #pragma unroll
        for (int h = 0; h < HH; ++h) vsL[h][tid] = vcol[h * NROW + j];
    }
    binL[tid] = b_in[tid];
    if (tid < 48) b2L[tid] = (tid < NC) ? bias2[tid] : 0.f;
    __syncthreads();

    // ---- phase 1: G[64][256] = A @ W_in, accumulate in regs ----
    const f32x4 zero4 = {0.f, 0.f, 0.f, 0.f};
    f32x4 accG[16];
    #pragma unroll
    for (int t = 0; t < 16; ++t) accG[t] = zero4;

    for (int kc = 0; kc < 8; ++kc) {
        // stage Wt chunk: Wbuf[n*40 + kk] = Wt[n][kc*32+kk]
        {
            const unsigned short* src = Wt + tid * DM + kc * 32;
            unsigned short* dst = &Wbuf[tid * 40];
            #pragma unroll
            for (int jq = 0; jq < 4; ++jq) {
                uint4 w4 = *(const uint4*)(src + jq * 8);
                *(uint4*)(dst + jq * 8) = w4;
            }
        }
        __syncthreads();
        bf16x8 af = *(const bf16x8*)&Abuf[(wv * 16 + lr) * 264 + kc * 32 + quad * 8];
        #pragma unroll
        for (int t = 0; t < 16; ++t) {
            bf16x8 bf = *(const bf16x8*)&Wbuf[(t * 16 + lr) * 40 + quad * 8];
            accG[t] = __builtin_amdgcn_mfma_f32_16x16x32_bf16(af, bf, accG[t], 0, 0, 0);
        }
        __syncthreads();
    }

    // ---- phase 2: in-register LN stats over all 4 heads ----
    float vh_r[HH][4];
    #pragma unroll
    for (int h = 0; h < HH; ++h)
        #pragma unroll
        for (int rg = 0; rg < 4; ++rg)
            vh_r[h][rg] = vsL[h][wv * 16 + quad * 4 + rg];
    float bcol[16];
    #pragma unroll
    for (int t = 0; t < 16; ++t) bcol[t] = binL[t * 16 + lr];

    float s[4] = {0.f, 0.f, 0.f, 0.f}, q2[4] = {0.f, 0.f, 0.f, 0.f};
    #pragma unroll
    for (int t = 0; t < 16; ++t)
        #pragma unroll
        for (int rg = 0; rg < 4; ++rg) {
            float gg = accG[t][rg];
            #pragma unroll
            for (int h = 0; h < HH; ++h) {
                float v = vh_r[h][rg];
                float y = v * fmaxf(fmaf(v, gg, bcol[t]), 0.f);
                s[rg] += y;
                q2[rg] = fmaf(y, y, q2[rg]);
            }
        }
    #pragma unroll
    for (int m = 1; m <= 8; m <<= 1)
        #pragma unroll
        for (int rg = 0; rg < 4; ++rg) {
            s[rg] += __shfl_xor(s[rg], m);
            q2[rg] += __shfl_xor(q2[rg], m);
        }
    float mu_[4], rs_[4];
    #pragma unroll
    for (int rg = 0; rg < 4; ++rg) {
        float m = s[rg] * (1.f / 1024.f);
        float var = q2[rg] * (1.f / 1024.f) - m * m;
        mu_[rg] = m;
        rs_[rg] = rsqrtf(var + 1e-5f);
    }

    // ---- phase 3: per-head LN-normalize -> LDS (bf16) -> head MFMA ----
    f32x4 accO[3];
    #pragma unroll
    for (int t = 0; t < 3; ++t) accO[t] = zero4;

    for (int h = 0; h < HH; ++h) {
        __syncthreads();   // protect Wbuf (and Abuf on h=0) from previous consumers
        // write z for this head into Abuf (wave-private rows)
        #pragma unroll
        for (int t = 0; t < 16; ++t)
            #pragma unroll
            for (int rg = 0; rg < 4; ++rg) {
                float v = vh_r[h][rg];
                float y = v * fmaxf(fmaf(v, accG[t][rg], bcol[t]), 0.f);
                float z = (y - mu_[rg]) * rs_[rg];
                Abuf[(wv * 16 + quad * 4 + rg) * 264 + t * 16 + lr] = f2bf(z);
            }
        // stage Wgt chunk for this head: Wbuf[c*264 + dd], zero-pad c>=40
        #pragma unroll
        for (int q = 0; q < 6; ++q) {
            int e = tid + 256 * q;
            int c = e >> 5;
            int dd = (e & 31) << 3;
            uint4 w4 = make_uint4(0u, 0u, 0u, 0u);
            if (c < NC) w4 = *(const uint4*)&Wgt[c * 1024 + h * DM + dd];
            *(uint4*)&Wbuf[c * 264 + dd] = w4;
        }
        __syncthreads();
        #pragma unroll
        for (int kc = 0; kc < 8; ++kc) {
            bf16x8 af = *(const bf16x8*)&Abuf[(wv * 16 + lr) * 264 + kc * 32 + quad * 8];
            #pragma unroll
            for (int t = 0; t < 3; ++t) {
                bf16x8 bf = *(const bf16x8*)&Wbuf[(t * 16 + lr) * 264 + kc * 32 + quad * 8];
                accO[t] = __builtin_amdgcn_mfma_f32_16x16x32_bf16(af, bf, accO[t], 0, 0, 0);
            }
        }
    }

    // ---- store ----
    #pragma unroll
    for (int t = 0; t < 3; ++t)
        #pragma unroll
        for (int rg = 0; rg < 4; ++rg) {
            int row = j0 + wv * 16 + quad * 4 + rg;
            int c = t * 16 + lr;
            if (row < NROW && c < NC)
                out[(size_t)row * NC + c] = accO[t][rg] + b2L[c];
        }
}

extern "C" void kernel_launch(void* const* d_in, const int* in_sizes, int n_in,
                              void* d_out, int out_size, void* d_ws, size_t ws_size,
                              hipStream_t stream) {
    const int*   pi    = (const int*)d_in[0];
    const float* pv    = (const float*)d_in[1];
    const float* feats = (const float*)d_in[2];
    const float* appd  = (const float*)d_in[3];
    const float* Win   = (const float*)d_in[4];
    const float* b_in  = (const float*)d_in[5];
    const float* gamma = (const float*)d_in[6];
    const float* beta  = (const float*)d_in[7];
    const float* Wh    = (const float*)d_in[8];
    const float* bh    = (const float*)d_in[9];
    float* out = (float*)d_out;

    char* w = (char*)d_ws;
    float*          vcolW  = (float*)w;                              // 800000 B
    float*          bias2W = (float*)(w + 800000);                   // 192 B
    unsigned short* WtW    = (unsigned short*)(w + 800192);          // 131072 B
    unsigned short* WgtW   = (unsigned short*)(w + 931264);          // 81920 B

    k_scatter<<<(BHN + 255) / 256, 256, 0, stream>>>(pi, pv, vcolW);
    k_prep_wt<<<DM, 256, 0, stream>>>(Win, WtW);
    k_prep_wh<<<NC, 256, 0, stream>>>(Wh, gamma, beta, bh, WgtW, bias2W);
    k_fused<<<NBLK, 256, 0, stream>>>(feats, appd, WtW, WgtW, vcolW, b_in, bias2W, out);
}